// Round 9
// baseline (238.714 us; speedup 1.0000x reference)
//
#include <hip/hip_runtime.h>

#define T_STEPS 345
#define B_SZ    128
#define IN_SZ   13
#define H_SZ    128
#define OUT_SZ  9
#define XT      348                 // xst row pitch (floats)
#define CPAD    388                 // cur2 LDS row pitch (floats); 97 float4s/row
#define NBO     (B_SZ * OUT_SZ)    // 1152
#define CHUNK   92                  // layer-1 t-chunk (4 chunks: 92,92,92,69)
#define BUFR    104                 // cur1 buffer rows (CHUNK + 12 prefetch overrun)

// v11: unified timeline, fixed wave roles, ZERO runtime div/mod.
// r8 lesson: v8/v10's scratch blowup (WRITE 171MB) tracks the graft loop with
// runtime idx%ntasks / idx/ntasks (absent in clean v5). This version keeps
// v5's code shapes exactly: one GEMM call site (wave 14, plain j-loop), one
// scan2 call site + tail (wave 15), emit on waves 2-13 (stride 6).
// Timeline (slot = barrier-to-barrier):
//   pre : emit c0 (all 16 waves, stride 8)
//   A k=0: scan1 c0 | emit c1
//   A k=1: scan1 c1 | emit c2 | GEMM s0 (w14)
//   A k=2: scan1 c2 | emit c3 | GEMM s1 (w14) | scan2 s0 (w15)
//   B s=2: scan1 c3 | GEMM s2 (w14) | scan2 s1 (w15)
//   B s=3..5:         GEMM s  (w14) | scan2 s-1 (w15)
//   tail:                             scan2 s5 (guarded)
// Readiness: GEMM stripe s at slot s+1 needs masks t<64(s+1); chunks 0..s cover
// t<92(s+1) ✓. scan2 reads stripes one barrier after they're written ✓.
// All per-element arithmetic sequences BIT-IDENTICAL to the passing v5.

__device__ __forceinline__ void emit_rows(float* __restrict__ buf,
                                          const float* __restrict__ xs,
                                          const float (&w1r)[IN_SZ], float b1r,
                                          int T0, int L, int h, int off, int stride)
{
    int tl = off;
    for (; tl + stride < L; tl += 2 * stride) {
        const int ta = T0 + tl, tb = T0 + tl + stride;
        float ca = b1r, cb = b1r;
#pragma unroll
        for (int c = 0; c < IN_SZ; ++c) {
            ca = fmaf(xs[c * XT + ta], w1r[c], ca);
            cb = fmaf(xs[c * XT + tb], w1r[c], cb);
        }
        buf[tl * H_SZ + h] = ca;
        buf[(tl + stride) * H_SZ + h] = cb;
    }
    if (tl < L) {
        const int ta = T0 + tl;
        float ca = b1r;
#pragma unroll
        for (int c = 0; c < IN_SZ; ++c) ca = fmaf(xs[c * XT + ta], w1r[c], ca);
        buf[tl * H_SZ + h] = ca;
    }
}

__device__ __forceinline__ void scan1_step(float& mem1, float u, float bt1, float th1,
                                           unsigned long long* __restrict__ msh,
                                           int t, bool sl, int half)
{
    mem1 = fmaf(bt1, mem1, u);
    const bool p = mem1 > th1;
    const unsigned long long m = __ballot(p);
    const float ms = mem1 - th1;            // == fmaf(-1, th1, mem1) bitwise
    mem1 = p ? ms : mem1;
    if (sl) msh[t * 2 + half] = m;
}

__device__ __forceinline__ void scan1_chunk(const float* __restrict__ buf,
                                            unsigned long long* __restrict__ msh,
                                            int T0, int L, int h,
                                            float bt1, float th1, float& mem1)
{
    const float* cb = buf + h;              // column h, row stride 128 floats
    const bool sl = (h & 63) == 0;
    const int half = h >> 6;
    // 12-row (3-group) rolling prefetch to cover LDS latency
    float a0 = cb[0*128], a1 = cb[1*128], a2 = cb[ 2*128], a3 = cb[ 3*128];
    float b0 = cb[4*128], b1v= cb[5*128], b2v= cb[ 6*128], b3 = cb[ 7*128];
    float c0 = cb[8*128], c1v= cb[9*128], c2v= cb[10*128], c3 = cb[11*128];
    const int fullg = L >> 2;
    const int rem   = L & 3;
    for (int g = 0; g < fullg; ++g) {
        const float u0 = a0, u1 = a1, u2 = a2, u3 = a3;
        a0 = b0; a1 = b1v; a2 = b2v; a3 = b3;
        b0 = c0; b1v = c1v; b2v = c2v; b3 = c3;
        const float* nb = cb + (g + 3) * 4 * 128;   // rows <= 103 < BUFR
        c0 = nb[0]; c1v = nb[128]; c2v = nb[256]; c3 = nb[384];
        const int tb = T0 + g * 4;
        scan1_step(mem1, u0, bt1, th1, msh, tb + 0, sl, half);
        scan1_step(mem1, u1, bt1, th1, msh, tb + 1, sl, half);
        scan1_step(mem1, u2, bt1, th1, msh, tb + 2, sl, half);
        scan1_step(mem1, u3, bt1, th1, msh, tb + 3, sl, half);
    }
    const int tb = T0 + fullg * 4;
    if (rem > 0) scan1_step(mem1, a0, bt1, th1, msh, tb + 0, sl, half);
    if (rem > 1) scan1_step(mem1, a1, bt1, th1, msh, tb + 1, sl, half);
    if (rem > 2) scan1_step(mem1, a2, bt1, th1, msh, tb + 2, sl, half);
}

// one (o, stripe) cur2 task; plain vector loads, h-chain 0..127
// BIT-IDENTICAL to verified kernels
__device__ __forceinline__ void cur2_stripe(int o, int s, int obase, int lane,
                                            const unsigned long long* __restrict__ msh,
                                            const float* __restrict__ W2,
                                            const float* __restrict__ b2,
                                            float* __restrict__ c2s)
{
    const int t  = s * 64 + lane;                             // < 384
    const int tc = (t < T_STEPS) ? t : (T_STEPS - 1);
    const uint4 mm = *(const uint4*)((const char*)msh + (size_t)tc * 16);
    const float* __restrict__ w2row = W2 + o * H_SZ;
    float acc = 0.0f;
#pragma unroll
    for (int h = 0; h < 32; ++h)
        acc = fmaf((float)((mm.x >> h) & 1u), w2row[h], acc);
#pragma unroll
    for (int h = 0; h < 32; ++h)
        acc = fmaf((float)((mm.y >> h) & 1u), w2row[32 + h], acc);
#pragma unroll
    for (int h = 0; h < 32; ++h)
        acc = fmaf((float)((mm.z >> h) & 1u), w2row[64 + h], acc);
#pragma unroll
    for (int h = 0; h < 32; ++h)
        acc = fmaf((float)((mm.w >> h) & 1u), w2row[96 + h], acc);
    c2s[(o - obase) * CPAD + t] = acc + b2[o];                // t<384<388 pad ok
}

// scan2 over one 64-step stripe (TAIL: guard tt<T_STEPS); inner math verbatim
template<bool TAIL>
__device__ __forceinline__ void scan2_stripe(const float4* __restrict__ src4, int s,
                                             float bt2, float th2, float& mem2,
                                             float* __restrict__ out_spk,
                                             float* __restrict__ out_mem)
{
    const int sb = s * 16;
    float4 fA = src4[sb], fB = src4[sb + 1];
#pragma unroll
    for (int i = 0; i < 16; ++i) {
        const float4 u = fA; fA = fB; fB = src4[sb + i + 2];   // <=src4[97]: next-row over-read, discarded
        const float vv[4] = { u.x, u.y, u.z, u.w };
#pragma unroll
        for (int kk = 0; kk < 4; ++kk) {
            const int tt = s * 64 + i * 4 + kk;
            if (!TAIL || tt < T_STEPS) {
                mem2 = fmaf(bt2, mem2, vv[kk]);
                const bool p = mem2 > th2;
                const float s2 = p ? 1.0f : 0.0f;
                const float ms = mem2 - th2;     // == fmaf(-1, th2, mem2) bitwise
                mem2 = p ? ms : mem2;
                out_spk[(size_t)tt * NBO] = s2;
                out_mem[(size_t)tt * NBO] = mem2;
            }
        }
    }
}

__global__ __launch_bounds__(1024, 1)
void snn_fused(const float* __restrict__ x, const float* __restrict__ W1,
               const float* __restrict__ b1, const float* __restrict__ W2,
               const float* __restrict__ b2,
               const float* __restrict__ beta1p, const float* __restrict__ thr1p,
               const float* __restrict__ beta2p, const float* __restrict__ thr2p,
               float* __restrict__ out)
{
    const int b    = blockIdx.x >> 1;
    const int half = blockIdx.x & 1;
    const int tid  = threadIdx.x;
    const int wid  = tid >> 6;
    const int lane = tid & 63;
    const int hown = tid & 127;              // owned hidden neuron
    const int jsl  = tid >> 7;               // 0..7 time-slot group

    __shared__ __align__(16) float xst[IN_SZ * XT];              // 18,096 B
    __shared__ __align__(16) float cur1s[2][BUFR * H_SZ];        // 106,496 B
    __shared__ __align__(16) unsigned long long msh[352 * 2];    //  5,632 B
    __shared__ __align__(16) float c2s[OUT_SZ * CPAD];           // 13,968 B
    // total 144,192 B -> 1 block/CU, 16 waves/CU

    // hoist scalar params (cold-miss latency overlaps staging)
    const float bt1 = fminf(fmaxf(beta1p[0], 0.0f), 1.0f);
    const float th1 = thr1p[0];
    const float bt2 = fminf(fmaxf(beta2p[0], 0.0f), 1.0f);
    const float th2 = thr2p[0];

    // ---------------- phase 0: stage x[b] (c-major) and W1^T into LDS ----------------
    const float* xb = x + (size_t)b * (IN_SZ * T_STEPS);
    for (int i = tid; i < IN_SZ * T_STEPS; i += 1024) {
        const int c = i / T_STEPS;
        const int t = i - c * T_STEPS;
        xst[c * XT + t] = xb[i];             // lane-consecutive t: conflict-free
    }
    float* W1t = c2s;   // c2s free until GEMM s0 (slot A1); holds W1t[c*128 + h]
    for (int i = tid; i < IN_SZ * H_SZ; i += 1024) {
        const int h = i / IN_SZ;
        const int c = i - IN_SZ * h;
        W1t[c * H_SZ + h] = W1[i];
    }
    __syncthreads();

    // ---------------- per-thread layer-1 weights (one h-row) ----------------
    float w1r[IN_SZ];
#pragma unroll
    for (int c = 0; c < IN_SZ; ++c) w1r[c] = W1t[c * H_SZ + hown];
    const float b1r = b1[hown];

    const int obase  = half ? 5 : 0;
    const int ntasks = half ? 4 : 5;
    const int L3     = T_STEPS - 3 * CHUNK;  // 69

    float mem1 = 0.0f;
    float mem2 = 0.0f;
    const int o_sc = obase + lane;                       // scanner's output row (wave 15)
    float* out_spk = out + (size_t)b * OUT_SZ + o_sc;
    float* out_mem = out_spk + (size_t)T_STEPS * NBO;
    const float4* src4 = (const float4*)(c2s + lane * CPAD);

    // pre: emit chunk 0 (all 16 waves, stride 8)
    emit_rows(cur1s[0], xst, w1r, b1r, 0, CHUNK, hown, jsl, 8);
    __syncthreads();

    // ---------------- loop A: slots k=0..2 ----------------
    for (int k = 0; k < 3; ++k) {
        if (tid < 128) {
            scan1_chunk(cur1s[k & 1], msh, k * CHUNK, CHUNK, tid, bt1, th1, mem1);
        } else if (wid < 14) {
            // waves 2-13: emit chunk k+1 (6-way t-interleave, jsl in 1..6)
            const int kn = k + 1;
            const int L = (kn < 3) ? CHUNK : L3;
            emit_rows(cur1s[kn & 1], xst, w1r, b1r, kn * CHUNK, L, hown, jsl - 1, 6);
        } else if (wid == 14) {
            if (k >= 1) {                    // GEMM stripe k-1 (masks t<92k ready)
                for (int j = 0; j < ntasks; ++j)
                    cur2_stripe(obase + j, k - 1, obase, lane, msh, W2, b2, c2s);
            }
        } else if (k == 2 && lane < ntasks) {
            scan2_stripe<false>(src4, 0, bt2, th2, mem2, out_spk, out_mem);
        }
        __syncthreads();
    }

    // ---------------- loop B: slots s=2..5 ----------------
    for (int s = 2; s <= 5; ++s) {
        if (tid < 128) {
            if (s == 2)                      // scan1 chunk 3 (final)
                scan1_chunk(cur1s[1], msh, 3 * CHUNK, L3, tid, bt1, th1, mem1);
        } else if (wid == 14) {
            for (int j = 0; j < ntasks; ++j)
                cur2_stripe(obase + j, s, obase, lane, msh, W2, b2, c2s);
        } else if (wid == 15 && lane < ntasks) {
            scan2_stripe<false>(src4, s - 1, bt2, th2, mem2, out_spk, out_mem);
        }
        __syncthreads();
    }

    // tail: scan2 stripe 5 (steps 320..344, guarded) — no trailing barrier
    if (wid == 15 && lane < ntasks) {
        scan2_stripe<true>(src4, 5, bt2, th2, mem2, out_spk, out_mem);
    }
}

extern "C" void kernel_launch(void* const* d_in, const int* in_sizes, int n_in,
                              void* d_out, int out_size, void* d_ws, size_t ws_size,
                              hipStream_t stream) {
    const float* x     = (const float*)d_in[0];
    const float* W1    = (const float*)d_in[1];
    const float* b1    = (const float*)d_in[2];
    const float* W2    = (const float*)d_in[3];
    const float* b2    = (const float*)d_in[4];
    const float* beta1 = (const float*)d_in[5];
    const float* thr1  = (const float*)d_in[6];
    const float* beta2 = (const float*)d_in[7];
    const float* thr2  = (const float*)d_in[8];
    float* out = (float*)d_out;
    (void)in_sizes; (void)n_in; (void)out_size; (void)d_ws; (void)ws_size;

    snn_fused<<<dim3(B_SZ * 2), dim3(1024), 0, stream>>>(
        x, W1, b1, W2, b2, beta1, thr1, beta2, thr2, out);
}

// Round 10
// 119.153 us; speedup vs baseline: 2.0034x; 2.0034x over previous
//
#include <hip/hip_runtime.h>

#define T_STEPS 345
#define B_SZ    128
#define IN_SZ   13
#define H_SZ    128
#define OUT_SZ  9
#define XT      348                 // xst row pitch (floats)
#define CPAD    388                 // cur2 LDS row pitch (floats); 97 float4s/row
#define NBO     (B_SZ * OUT_SZ)    // 1152
#define CHUNK   92                  // layer-1 t-chunk (4 chunks: 92,92,92,69)
#define BUFR    104                 // cur1 buffer rows (CHUNK + 12 prefetch overrun)

// v12 = v5 VERBATIM + one graft, single-variable test.
// r9 ledger: v5 clean (40us, WRITE 8MB); v8/v10/v11 all scratch-blown (171-289MB).
// Surviving hypothesis: the trigger is a RUNTIME-TRIP cur2 loop nested in shared
// control flow (v5's clean slot loop has exactly one cur2 call, no inner loop).
// This version grafts ONLY: peeled k=3 slot where waves 2..2+ntasks-1 each take
// ONE fixed o and run a #pragma-unroll(3) stripe loop (compile-time trip, one
// call site). Phase 2/3 keeps v5's exact per-slot shape, shifted:
//   peel : scan1 c3 | GEMM s0,s1,s2 (one o per wave, unroll 3)
//   u=0..4: GEMM s3+u (u<3, waves 0..ntasks-1) | scan2 su (wave 15)
//   tail : scan2 s5 (guarded)
// All per-element arithmetic sequences BIT-IDENTICAL to the passing v5.

__device__ __forceinline__ void emit_rows(float* __restrict__ buf,
                                          const float* __restrict__ xs,
                                          const float (&w1r)[IN_SZ], float b1r,
                                          int T0, int L, int h, int off, int stride)
{
    int tl = off;
    for (; tl + stride < L; tl += 2 * stride) {
        const int ta = T0 + tl, tb = T0 + tl + stride;
        float ca = b1r, cb = b1r;
#pragma unroll
        for (int c = 0; c < IN_SZ; ++c) {
            ca = fmaf(xs[c * XT + ta], w1r[c], ca);
            cb = fmaf(xs[c * XT + tb], w1r[c], cb);
        }
        buf[tl * H_SZ + h] = ca;
        buf[(tl + stride) * H_SZ + h] = cb;
    }
    if (tl < L) {
        const int ta = T0 + tl;
        float ca = b1r;
#pragma unroll
        for (int c = 0; c < IN_SZ; ++c) ca = fmaf(xs[c * XT + ta], w1r[c], ca);
        buf[tl * H_SZ + h] = ca;
    }
}

__device__ __forceinline__ void scan1_step(float& mem1, float u, float bt1, float th1,
                                           unsigned long long* __restrict__ msh,
                                           int t, bool sl, int half)
{
    mem1 = fmaf(bt1, mem1, u);
    const bool p = mem1 > th1;
    const unsigned long long m = __ballot(p);
    const float ms = mem1 - th1;            // == fmaf(-1, th1, mem1) bitwise
    mem1 = p ? ms : mem1;
    if (sl) msh[t * 2 + half] = m;
}

__device__ __forceinline__ void scan1_chunk(const float* __restrict__ buf,
                                            unsigned long long* __restrict__ msh,
                                            int T0, int L, int h,
                                            float bt1, float th1, float& mem1)
{
    const float* cb = buf + h;              // column h, row stride 128 floats
    const bool sl = (h & 63) == 0;
    const int half = h >> 6;
    // 12-row (3-group) rolling prefetch to cover LDS latency
    float a0 = cb[0*128], a1 = cb[1*128], a2 = cb[ 2*128], a3 = cb[ 3*128];
    float b0 = cb[4*128], b1v= cb[5*128], b2v= cb[ 6*128], b3 = cb[ 7*128];
    float c0 = cb[8*128], c1v= cb[9*128], c2v= cb[10*128], c3 = cb[11*128];
    const int fullg = L >> 2;
    const int rem   = L & 3;
    for (int g = 0; g < fullg; ++g) {
        const float u0 = a0, u1 = a1, u2 = a2, u3 = a3;
        a0 = b0; a1 = b1v; a2 = b2v; a3 = b3;
        b0 = c0; b1v = c1v; b2v = c2v; b3 = c3;
        const float* nb = cb + (g + 3) * 4 * 128;   // rows <= 103 < BUFR
        c0 = nb[0]; c1v = nb[128]; c2v = nb[256]; c3 = nb[384];
        const int tb = T0 + g * 4;
        scan1_step(mem1, u0, bt1, th1, msh, tb + 0, sl, half);
        scan1_step(mem1, u1, bt1, th1, msh, tb + 1, sl, half);
        scan1_step(mem1, u2, bt1, th1, msh, tb + 2, sl, half);
        scan1_step(mem1, u3, bt1, th1, msh, tb + 3, sl, half);
    }
    const int tb = T0 + fullg * 4;
    if (rem > 0) scan1_step(mem1, a0, bt1, th1, msh, tb + 0, sl, half);
    if (rem > 1) scan1_step(mem1, a1, bt1, th1, msh, tb + 1, sl, half);
    if (rem > 2) scan1_step(mem1, a2, bt1, th1, msh, tb + 2, sl, half);
}

// one (o, stripe) cur2 task; plain vector loads, h-chain 0..127
// BIT-IDENTICAL to verified kernels
__device__ __forceinline__ void cur2_stripe(int o, int s, int obase, int lane,
                                            const unsigned long long* __restrict__ msh,
                                            const float* __restrict__ W2,
                                            const float* __restrict__ b2,
                                            float* __restrict__ c2s)
{
    const int t  = s * 64 + lane;                             // < 384
    const int tc = (t < T_STEPS) ? t : (T_STEPS - 1);
    const uint4 mm = *(const uint4*)((const char*)msh + (size_t)tc * 16);
    const float* __restrict__ w2row = W2 + o * H_SZ;
    float acc = 0.0f;
#pragma unroll
    for (int h = 0; h < 32; ++h)
        acc = fmaf((float)((mm.x >> h) & 1u), w2row[h], acc);
#pragma unroll
    for (int h = 0; h < 32; ++h)
        acc = fmaf((float)((mm.y >> h) & 1u), w2row[32 + h], acc);
#pragma unroll
    for (int h = 0; h < 32; ++h)
        acc = fmaf((float)((mm.z >> h) & 1u), w2row[64 + h], acc);
#pragma unroll
    for (int h = 0; h < 32; ++h)
        acc = fmaf((float)((mm.w >> h) & 1u), w2row[96 + h], acc);
    c2s[(o - obase) * CPAD + t] = acc + b2[o];                // t<384<388 pad ok
}

// scan2 over one 64-step stripe (TAIL: guard tt<T_STEPS); inner math verbatim
template<bool TAIL>
__device__ __forceinline__ void scan2_stripe(const float4* __restrict__ src4, int s,
                                             float bt2, float th2, float& mem2,
                                             float* __restrict__ out_spk,
                                             float* __restrict__ out_mem)
{
    const int sb = s * 16;
    float4 fA = src4[sb], fB = src4[sb + 1];
#pragma unroll
    for (int i = 0; i < 16; ++i) {
        const float4 u = fA; fA = fB; fB = src4[sb + i + 2];   // <=src4[97]: next-row over-read, discarded
        const float vv[4] = { u.x, u.y, u.z, u.w };
#pragma unroll
        for (int kk = 0; kk < 4; ++kk) {
            const int tt = s * 64 + i * 4 + kk;
            if (!TAIL || tt < T_STEPS) {
                mem2 = fmaf(bt2, mem2, vv[kk]);
                const bool p = mem2 > th2;
                const float s2 = p ? 1.0f : 0.0f;
                const float ms = mem2 - th2;     // == fmaf(-1, th2, mem2) bitwise
                mem2 = p ? ms : mem2;
                out_spk[(size_t)tt * NBO] = s2;
                out_mem[(size_t)tt * NBO] = mem2;
            }
        }
    }
}

__global__ __launch_bounds__(1024, 1)
void snn_fused(const float* __restrict__ x, const float* __restrict__ W1,
               const float* __restrict__ b1, const float* __restrict__ W2,
               const float* __restrict__ b2,
               const float* __restrict__ beta1p, const float* __restrict__ thr1p,
               const float* __restrict__ beta2p, const float* __restrict__ thr2p,
               float* __restrict__ out)
{
    const int b    = blockIdx.x >> 1;
    const int half = blockIdx.x & 1;
    const int tid  = threadIdx.x;
    const int wid  = tid >> 6;
    const int lane = tid & 63;
    const int hown = tid & 127;              // owned hidden neuron
    const int jsl  = tid >> 7;               // 0..7 time-slot group

    __shared__ __align__(16) float xst[IN_SZ * XT];              // 18,096 B
    __shared__ __align__(16) float cur1s[2][BUFR * H_SZ];        // 106,496 B
    __shared__ __align__(16) unsigned long long msh[352 * 2];    //  5,632 B
    __shared__ __align__(16) float c2s[OUT_SZ * CPAD];           // 13,968 B
    // total 144,192 B -> 1 block/CU, 16 waves/CU

    // hoist scalar params (cold-miss latency overlaps staging)
    const float bt1 = fminf(fmaxf(beta1p[0], 0.0f), 1.0f);
    const float th1 = thr1p[0];
    const float bt2 = fminf(fmaxf(beta2p[0], 0.0f), 1.0f);
    const float th2 = thr2p[0];

    // ---------------- phase 0: stage x[b] (c-major) and W1^T into LDS ----------------
    const float* xb = x + (size_t)b * (IN_SZ * T_STEPS);
    for (int i = tid; i < IN_SZ * T_STEPS; i += 1024) {
        const int c = i / T_STEPS;
        const int t = i - c * T_STEPS;
        xst[c * XT + t] = xb[i];             // lane-consecutive t: conflict-free
    }
    float* W1t = c2s;   // c2s free until the peel slot's GEMM; holds W1t[c*128 + h]
    for (int i = tid; i < IN_SZ * H_SZ; i += 1024) {
        const int h = i / IN_SZ;
        const int c = i - IN_SZ * h;
        W1t[c * H_SZ + h] = W1[i];
    }
    __syncthreads();

    // ---------------- per-thread layer-1 weights (one h-row) ----------------
    float w1r[IN_SZ];
#pragma unroll
    for (int c = 0; c < IN_SZ; ++c) w1r[c] = W1t[c * H_SZ + hown];
    const float b1r = b1[hown];

    const int obase  = half ? 5 : 0;
    const int ntasks = half ? 4 : 5;
    const int L3     = T_STEPS - 3 * CHUNK;  // 69

    // ---------------- phase 1: k-loop k=0..2 (v5 body verbatim) ----------------
    emit_rows(cur1s[0], xst, w1r, b1r, 0, CHUNK, hown, jsl, 8);
    __syncthreads();

    float mem1 = 0.0f;
    for (int k = 0; k < 3; ++k) {
        if (tid < 128) {
            scan1_chunk(cur1s[k & 1], msh, k * CHUNK, CHUNK, tid, bt1, th1, mem1);
        } else {
            // waves 2-15: emit chunk k+1 (7-way t-interleave, jsl in 1..7)
            const int kn = k + 1;
            const int L = (kn < 3) ? CHUNK : L3;
            emit_rows(cur1s[kn & 1], xst, w1r, b1r, kn * CHUNK, L, hown, jsl - 1, 7);
        }
        __syncthreads();
    }

    // ---------------- peeled k=3: scan1 c3 | GEMM stripes 0-2 ----------------
    // One FIXED o per wave (waves 2..2+ntasks-1), compile-time-trip stripe loop.
    // Masks for stripes 0-2 (t<192) covered by chunks 0-2 (t<276) ✓.
    if (tid < 128) {
        scan1_chunk(cur1s[1], msh, 3 * CHUNK, L3, tid, bt1, th1, mem1);
    } else if (wid - 2 < ntasks) {
        const int o = obase + (wid - 2);
#pragma unroll
        for (int s = 0; s < 3; ++s)
            cur2_stripe(o, s, obase, lane, msh, W2, b2, c2s);
    }
    __syncthreads();

    // ---------------- phase 2/3: 5 slots + tail (v5 per-slot shape) ----------------
    float mem2 = 0.0f;
    const int o_sc = obase + lane;                       // scanner's output row (wave 15)
    float* out_spk = out + (size_t)b * OUT_SZ + o_sc;
    float* out_mem = out_spk + (size_t)T_STEPS * NBO;
    const float4* src4 = (const float4*)(c2s + lane * CPAD);

    for (int u = 0; u < 5; ++u) {
        if (wid < ntasks) {
            if (u < 3) cur2_stripe(obase + wid, 3 + u, obase, lane, msh, W2, b2, c2s);
        } else if (wid == 15 && lane < ntasks) {
            scan2_stripe<false>(src4, u, bt2, th2, mem2, out_spk, out_mem);
        }
        __syncthreads();
    }

    // tail: scan2 stripe 5 (steps 320..344, guarded) — no trailing barrier
    if (wid == 15 && lane < ntasks) {
        scan2_stripe<true>(src4, 5, bt2, th2, mem2, out_spk, out_mem);
    }
}

extern "C" void kernel_launch(void* const* d_in, const int* in_sizes, int n_in,
                              void* d_out, int out_size, void* d_ws, size_t ws_size,
                              hipStream_t stream) {
    const float* x     = (const float*)d_in[0];
    const float* W1    = (const float*)d_in[1];
    const float* b1    = (const float*)d_in[2];
    const float* W2    = (const float*)d_in[3];
    const float* b2    = (const float*)d_in[4];
    const float* beta1 = (const float*)d_in[5];
    const float* thr1  = (const float*)d_in[6];
    const float* beta2 = (const float*)d_in[7];
    const float* thr2  = (const float*)d_in[8];
    float* out = (float*)d_out;
    (void)in_sizes; (void)n_in; (void)out_size; (void)d_ws; (void)ws_size;

    snn_fused<<<dim3(B_SZ * 2), dim3(1024), 0, stream>>>(
        x, W1, b1, W2, b2, beta1, thr1, beta2, thr2, out);
}

// Round 13
// 103.592 us; speedup vs baseline: 2.3044x; 1.1502x over previous
//
#include <hip/hip_runtime.h>

#define T_STEPS 345
#define B_SZ    128
#define IN_SZ   13
#define H_SZ    128
#define OUT_SZ  9
#define XT      348                 // xst row pitch (floats)
#define CPAD    388                 // cur2 LDS row pitch (floats)
#define NBO     (B_SZ * OUT_SZ)    // 1152
#define CHUNK   92                  // layer-1 t-chunk (4 chunks: 92,92,92,69)
#define BUFR    104                 // cur1 buffer rows (CHUNK + 12 prefetch overrun)

// v15 == v14 == v13 == v5 verbatim (session optimum: 40.4us kernel / 103.47us
// total, verified passing in round 4). r11/r12 were infrastructure failures
// (container acquisition), not kernel failures — identical source resubmitted.
// SESSION LEDGER (do not retry without new evidence):
//  - v5 structure: 1024 thr/block, 2 blocks/batch; phase1 {scan1 w0-1 || emit
//    w2-15} x4 chunks; phase2/3 {GEMM w0-4 || scan2 w7} x6 stripes. CLEAN:
//    VGPR 56, WRITE 7.9MB, no scratch.
//  - CONDEMNED: any graft of cur2/scan2 into control regions shared with
//    emit/scan1 (v8/v10/v11/v12). hipcc pins VGPR at 64 and spills instead of
//    growing: WRITE_SIZE 37-289MB scratch, cold first dispatch, +16-120us.
//    Refuted sub-theories: loop-carried w1r (v10), runtime div/mod (v11),
//    runtime-trip inner loop (v12). Tripwire: WRITE_SIZE >> 8MB.
//  - readfirstlane->s_load W2 scalarization: -5us regression (v6).
//  - Remaining headroom (~40 -> ~20us span arithmetic) is blocked by the
//    above compiler behavior, not by hardware limits.
// All per-element arithmetic sequences BIT-IDENTICAL to the verified chain
// (R1/R4/R6 -> v4 -> v5): knife-edge numerics, do not reorder.

__device__ __forceinline__ void emit_rows(float* __restrict__ buf,
                                          const float* __restrict__ xs,
                                          const float (&w1r)[IN_SZ], float b1r,
                                          int T0, int L, int h, int off, int stride)
{
    int tl = off;
    for (; tl + stride < L; tl += 2 * stride) {
        const int ta = T0 + tl, tb = T0 + tl + stride;
        float ca = b1r, cb = b1r;
#pragma unroll
        for (int c = 0; c < IN_SZ; ++c) {
            ca = fmaf(xs[c * XT + ta], w1r[c], ca);
            cb = fmaf(xs[c * XT + tb], w1r[c], cb);
        }
        buf[tl * H_SZ + h] = ca;
        buf[(tl + stride) * H_SZ + h] = cb;
    }
    if (tl < L) {
        const int ta = T0 + tl;
        float ca = b1r;
#pragma unroll
        for (int c = 0; c < IN_SZ; ++c) ca = fmaf(xs[c * XT + ta], w1r[c], ca);
        buf[tl * H_SZ + h] = ca;
    }
}

__device__ __forceinline__ void scan1_step(float& mem1, float u, float bt1, float th1,
                                           unsigned long long* __restrict__ msh,
                                           int t, bool sl, int half)
{
    mem1 = fmaf(bt1, mem1, u);
    const bool p = mem1 > th1;
    const unsigned long long m = __ballot(p);
    const float ms = mem1 - th1;            // == fmaf(-1, th1, mem1) bitwise
    mem1 = p ? ms : mem1;
    if (sl) msh[t * 2 + half] = m;
}

__device__ __forceinline__ void scan1_chunk(const float* __restrict__ buf,
                                            unsigned long long* __restrict__ msh,
                                            int T0, int L, int h,
                                            float bt1, float th1, float& mem1)
{
    const float* cb = buf + h;              // column h, row stride 128 floats
    const bool sl = (h & 63) == 0;
    const int half = h >> 6;
    // 12-row (3-group) rolling prefetch to cover LDS latency
    float a0 = cb[0*128], a1 = cb[1*128], a2 = cb[ 2*128], a3 = cb[ 3*128];
    float b0 = cb[4*128], b1v= cb[5*128], b2v= cb[ 6*128], b3 = cb[ 7*128];
    float c0 = cb[8*128], c1v= cb[9*128], c2v= cb[10*128], c3 = cb[11*128];
    const int fullg = L >> 2;
    const int rem   = L & 3;
    for (int g = 0; g < fullg; ++g) {
        const float u0 = a0, u1 = a1, u2 = a2, u3 = a3;
        a0 = b0; a1 = b1v; a2 = b2v; a3 = b3;
        b0 = c0; b1v = c1v; b2v = c2v; b3 = c3;
        const float* nb = cb + (g + 3) * 4 * 128;   // rows <= 103 < BUFR
        c0 = nb[0]; c1v = nb[128]; c2v = nb[256]; c3 = nb[384];
        const int tb = T0 + g * 4;
        scan1_step(mem1, u0, bt1, th1, msh, tb + 0, sl, half);
        scan1_step(mem1, u1, bt1, th1, msh, tb + 1, sl, half);
        scan1_step(mem1, u2, bt1, th1, msh, tb + 2, sl, half);
        scan1_step(mem1, u3, bt1, th1, msh, tb + 3, sl, half);
    }
    const int tb = T0 + fullg * 4;
    if (rem > 0) scan1_step(mem1, a0, bt1, th1, msh, tb + 0, sl, half);
    if (rem > 1) scan1_step(mem1, a1, bt1, th1, msh, tb + 1, sl, half);
    if (rem > 2) scan1_step(mem1, a2, bt1, th1, msh, tb + 2, sl, half);
}

__global__ __launch_bounds__(1024, 1)
void snn_fused(const float* __restrict__ x, const float* __restrict__ W1,
               const float* __restrict__ b1, const float* __restrict__ W2,
               const float* __restrict__ b2,
               const float* __restrict__ beta1p, const float* __restrict__ thr1p,
               const float* __restrict__ beta2p, const float* __restrict__ thr2p,
               float* __restrict__ out)
{
    const int b    = blockIdx.x >> 1;
    const int half = blockIdx.x & 1;
    const int tid  = threadIdx.x;
    const int wid  = tid >> 6;
    const int lane = tid & 63;
    const int hown = tid & 127;              // owned hidden neuron
    const int jsl  = tid >> 7;               // 0..7 time-slot group

    __shared__ __align__(16) float xst[IN_SZ * XT];              // 18,096 B
    __shared__ __align__(16) float cur1s[2][BUFR * H_SZ];        // 106,496 B
    __shared__ __align__(16) unsigned long long msh[352 * 2];    //  5,632 B
    __shared__ __align__(16) float c2s[OUT_SZ * CPAD];           // 13,968 B
    // total 144,192 B -> 1 block/CU, 16 waves/CU

    // hoist scalar params (cold-miss latency overlaps staging)
    const float bt1 = fminf(fmaxf(beta1p[0], 0.0f), 1.0f);
    const float th1 = thr1p[0];
    const float bt2 = fminf(fmaxf(beta2p[0], 0.0f), 1.0f);
    const float th2 = thr2p[0];

    // ---------------- phase 0: stage x[b] (c-major) and W1^T into LDS ----------------
    const float* xb = x + (size_t)b * (IN_SZ * T_STEPS);
    for (int i = tid; i < IN_SZ * T_STEPS; i += 1024) {
        const int c = i / T_STEPS;
        const int t = i - c * T_STEPS;
        xst[c * XT + t] = xb[i];             // lane-consecutive t: conflict-free
    }
    float* W1t = c2s;   // c2s free until phase 2; holds W1t[c*128 + h]
    for (int i = tid; i < IN_SZ * H_SZ; i += 1024) {
        const int h = i / IN_SZ;
        const int c = i - IN_SZ * h;
        W1t[c * H_SZ + h] = W1[i];
    }
    __syncthreads();

    // ---------------- per-thread layer-1 weights (one h-row) ----------------
    float w1r[IN_SZ];
#pragma unroll
    for (int c = 0; c < IN_SZ; ++c) w1r[c] = W1t[c * H_SZ + hown];
    const float b1r = b1[hown];

    // ---------------- phase 1: chunked cur1 GEMM pipelined with mem1 scan ----------------
    // chunk 0: all 16 waves emit (8-way t-interleave)
    emit_rows(cur1s[0], xst, w1r, b1r, 0, CHUNK, hown, jsl, 8);
    __syncthreads();

    float mem1 = 0.0f;
    for (int k = 0; k < 4; ++k) {
        if (tid < 128) {
            const int L = (k < 3) ? CHUNK : (T_STEPS - 3 * CHUNK);
            scan1_chunk(cur1s[k & 1], msh, k * CHUNK, L, tid, bt1, th1, mem1);
        } else if (k < 3) {
            // waves 2-15: emit chunk k+1 (7-way t-interleave, jsl in 1..7)
            const int kn = k + 1;
            const int L = (kn < 3) ? CHUNK : (T_STEPS - 3 * CHUNK);
            emit_rows(cur1s[kn & 1], xst, w1r, b1r, kn * CHUNK, L, hown, jsl - 1, 7);
        }
        __syncthreads();
    }

    // ---------------- phase 2/3: stripe-pipelined cur2 GEMM + mem2 scan ----------------
    const int obase  = half ? 5 : 0;
    const int ntasks = half ? 4 : 5;

    float mem2 = 0.0f;
    const int o_sc = obase + lane;                       // scanner's output row (wave 7)
    float* out_spk = out + (size_t)b * OUT_SZ + o_sc;
    float* out_mem = out_spk + (size_t)T_STEPS * NBO;
    const float4* src4 = (const float4*)(c2s + lane * CPAD);

    for (int s = 0; s < 6; ++s) {
        if (wid < 7) {
            if (wid < ntasks) {
                const int o = obase + wid;
                const int t = s * 64 + lane;
                const int tc = (t < T_STEPS) ? t : (T_STEPS - 1);
                const uint4 mm = *(const uint4*)((const char*)msh + (size_t)tc * 16);
                const float* __restrict__ w2row = W2 + o * H_SZ;
                float acc = 0.0f;
#pragma unroll
                for (int h = 0; h < 32; ++h)
                    acc = fmaf((float)((mm.x >> h) & 1u), w2row[h], acc);
#pragma unroll
                for (int h = 0; h < 32; ++h)
                    acc = fmaf((float)((mm.y >> h) & 1u), w2row[32 + h], acc);
#pragma unroll
                for (int h = 0; h < 32; ++h)
                    acc = fmaf((float)((mm.z >> h) & 1u), w2row[64 + h], acc);
#pragma unroll
                for (int h = 0; h < 32; ++h)
                    acc = fmaf((float)((mm.w >> h) & 1u), w2row[96 + h], acc);
                c2s[wid * CPAD + t] = acc + b2[o];
            }
        } else if (wid == 7 && s > 0 && lane < ntasks) {
            // scan stripe s-1 (stripes 0..4 fully in-range)
            const int sb = (s - 1) * 16;
            float4 fA = src4[sb], fB = src4[sb + 1];
#pragma unroll
            for (int i = 0; i < 16; ++i) {
                const float4 u = fA; fA = fB; fB = src4[sb + i + 2];
                const float vv[4] = { u.x, u.y, u.z, u.w };
#pragma unroll
                for (int kk = 0; kk < 4; ++kk) {
                    const int tt = (s - 1) * 64 + i * 4 + kk;
                    mem2 = fmaf(bt2, mem2, vv[kk]);
                    const bool p = mem2 > th2;
                    const float s2 = p ? 1.0f : 0.0f;
                    const float ms = mem2 - th2;     // == fmaf(-1, th2, mem2) bitwise
                    mem2 = p ? ms : mem2;
                    out_spk[(size_t)tt * NBO] = s2;
                    out_mem[(size_t)tt * NBO] = mem2;
                }
            }
        }
        __syncthreads();
    }

    // tail: scan stripe 5 (steps 320..344, guarded)
    if (wid == 7 && lane < ntasks) {
        const int sb = 5 * 16;
        float4 fA = src4[sb], fB = src4[sb + 1];
#pragma unroll
        for (int i = 0; i < 16; ++i) {
            const float4 u = fA; fA = fB; fB = src4[sb + i + 2];   // over-read in-bounds, discarded
            const float vv[4] = { u.x, u.y, u.z, u.w };
#pragma unroll
            for (int kk = 0; kk < 4; ++kk) {
                const int tt = 5 * 64 + i * 4 + kk;
                if (tt < T_STEPS) {
                    mem2 = fmaf(bt2, mem2, vv[kk]);
                    const bool p = mem2 > th2;
                    const float s2 = p ? 1.0f : 0.0f;
                    const float ms = mem2 - th2;
                    mem2 = p ? ms : mem2;
                    out_spk[(size_t)tt * NBO] = s2;
                    out_mem[(size_t)tt * NBO] = mem2;
                }
            }
        }
    }
}

extern "C" void kernel_launch(void* const* d_in, const int* in_sizes, int n_in,
                              void* d_out, int out_size, void* d_ws, size_t ws_size,
                              hipStream_t stream) {
    const float* x     = (const float*)d_in[0];
    const float* W1    = (const float*)d_in[1];
    const float* b1    = (const float*)d_in[2];
    const float* W2    = (const float*)d_in[3];
    const float* b2    = (const float*)d_in[4];
    const float* beta1 = (const float*)d_in[5];
    const float* thr1  = (const float*)d_in[6];
    const float* beta2 = (const float*)d_in[7];
    const float* thr2  = (const float*)d_in[8];
    float* out = (float*)d_out;
    (void)in_sizes; (void)n_in; (void)out_size; (void)d_ws; (void)ws_size;

    snn_fused<<<dim3(B_SZ * 2), dim3(1024), 0, stream>>>(
        x, W1, b1, W2, b2, beta1, thr1, beta2, thr2, out);
}

// Round 14
// 103.187 us; speedup vs baseline: 2.3134x; 1.0039x over previous
//
#include <hip/hip_runtime.h>

#define T_STEPS 345
#define B_SZ    128
#define IN_SZ   13
#define H_SZ    128
#define OUT_SZ  9
#define XT      348                 // xst row pitch (floats)
#define CPAD    388                 // cur2 LDS row pitch (floats)
#define NBO     (B_SZ * OUT_SZ)    // 1152
#define CHUNK   92                  // layer-1 t-chunk (4 chunks: 92,92,92,69)
#define BUFR    104                 // cur1 buffer rows (CHUNK + 12 prefetch overrun)

// v16 = v5 verbatim + s_setprio(1) around the serial scan bodies (T5 graft —
// scheduling hint only, no structural change, no arithmetic change).
// Rationale: scanner waves (0-1 in phase 1, wave 7 in phase 2/3) carry the
// dependent recurrence chains and share SIMDs with 3x emit/GEMM waves; wave
// priority cuts round-robin issue latency on the critical chain.
// SESSION LEDGER (do not retry without new evidence):
//  - v5 structure CLEAN: VGPR 56, WRITE 7.9MB, timed total 103.5us (kernel ~40).
//  - CONDEMNED: any graft of cur2/scan2 into control regions shared with
//    emit/scan1 (v8/v10/v11/v12): hipcc pins VGPR at 64 and spills ->
//    WRITE_SIZE 37-289MB scratch. Tripwire: WRITE_SIZE >> 8MB.
//  - readfirstlane->s_load W2 scalarization: -5us regression (v6).
//  - Profiled dur is DVFS-noisy (40.4 vs 75us at identical timed totals);
//    trust timed dur_us and the issue-time invariant (~13-15us).
// All per-element arithmetic sequences BIT-IDENTICAL to the verified chain.

__device__ __forceinline__ void emit_rows(float* __restrict__ buf,
                                          const float* __restrict__ xs,
                                          const float (&w1r)[IN_SZ], float b1r,
                                          int T0, int L, int h, int off, int stride)
{
    int tl = off;
    for (; tl + stride < L; tl += 2 * stride) {
        const int ta = T0 + tl, tb = T0 + tl + stride;
        float ca = b1r, cb = b1r;
#pragma unroll
        for (int c = 0; c < IN_SZ; ++c) {
            ca = fmaf(xs[c * XT + ta], w1r[c], ca);
            cb = fmaf(xs[c * XT + tb], w1r[c], cb);
        }
        buf[tl * H_SZ + h] = ca;
        buf[(tl + stride) * H_SZ + h] = cb;
    }
    if (tl < L) {
        const int ta = T0 + tl;
        float ca = b1r;
#pragma unroll
        for (int c = 0; c < IN_SZ; ++c) ca = fmaf(xs[c * XT + ta], w1r[c], ca);
        buf[tl * H_SZ + h] = ca;
    }
}

__device__ __forceinline__ void scan1_step(float& mem1, float u, float bt1, float th1,
                                           unsigned long long* __restrict__ msh,
                                           int t, bool sl, int half)
{
    mem1 = fmaf(bt1, mem1, u);
    const bool p = mem1 > th1;
    const unsigned long long m = __ballot(p);
    const float ms = mem1 - th1;            // == fmaf(-1, th1, mem1) bitwise
    mem1 = p ? ms : mem1;
    if (sl) msh[t * 2 + half] = m;
}

__device__ __forceinline__ void scan1_chunk(const float* __restrict__ buf,
                                            unsigned long long* __restrict__ msh,
                                            int T0, int L, int h,
                                            float bt1, float th1, float& mem1)
{
    const float* cb = buf + h;              // column h, row stride 128 floats
    const bool sl = (h & 63) == 0;
    const int half = h >> 6;
    // 12-row (3-group) rolling prefetch to cover LDS latency
    float a0 = cb[0*128], a1 = cb[1*128], a2 = cb[ 2*128], a3 = cb[ 3*128];
    float b0 = cb[4*128], b1v= cb[5*128], b2v= cb[ 6*128], b3 = cb[ 7*128];
    float c0 = cb[8*128], c1v= cb[9*128], c2v= cb[10*128], c3 = cb[11*128];
    const int fullg = L >> 2;
    const int rem   = L & 3;
    for (int g = 0; g < fullg; ++g) {
        const float u0 = a0, u1 = a1, u2 = a2, u3 = a3;
        a0 = b0; a1 = b1v; a2 = b2v; a3 = b3;
        b0 = c0; b1v = c1v; b2v = c2v; b3 = c3;
        const float* nb = cb + (g + 3) * 4 * 128;   // rows <= 103 < BUFR
        c0 = nb[0]; c1v = nb[128]; c2v = nb[256]; c3 = nb[384];
        const int tb = T0 + g * 4;
        scan1_step(mem1, u0, bt1, th1, msh, tb + 0, sl, half);
        scan1_step(mem1, u1, bt1, th1, msh, tb + 1, sl, half);
        scan1_step(mem1, u2, bt1, th1, msh, tb + 2, sl, half);
        scan1_step(mem1, u3, bt1, th1, msh, tb + 3, sl, half);
    }
    const int tb = T0 + fullg * 4;
    if (rem > 0) scan1_step(mem1, a0, bt1, th1, msh, tb + 0, sl, half);
    if (rem > 1) scan1_step(mem1, a1, bt1, th1, msh, tb + 1, sl, half);
    if (rem > 2) scan1_step(mem1, a2, bt1, th1, msh, tb + 2, sl, half);
}

__global__ __launch_bounds__(1024, 1)
void snn_fused(const float* __restrict__ x, const float* __restrict__ W1,
               const float* __restrict__ b1, const float* __restrict__ W2,
               const float* __restrict__ b2,
               const float* __restrict__ beta1p, const float* __restrict__ thr1p,
               const float* __restrict__ beta2p, const float* __restrict__ thr2p,
               float* __restrict__ out)
{
    const int b    = blockIdx.x >> 1;
    const int half = blockIdx.x & 1;
    const int tid  = threadIdx.x;
    const int wid  = tid >> 6;
    const int lane = tid & 63;
    const int hown = tid & 127;              // owned hidden neuron
    const int jsl  = tid >> 7;               // 0..7 time-slot group

    __shared__ __align__(16) float xst[IN_SZ * XT];              // 18,096 B
    __shared__ __align__(16) float cur1s[2][BUFR * H_SZ];        // 106,496 B
    __shared__ __align__(16) unsigned long long msh[352 * 2];    //  5,632 B
    __shared__ __align__(16) float c2s[OUT_SZ * CPAD];           // 13,968 B
    // total 144,192 B -> 1 block/CU, 16 waves/CU

    // hoist scalar params (cold-miss latency overlaps staging)
    const float bt1 = fminf(fmaxf(beta1p[0], 0.0f), 1.0f);
    const float th1 = thr1p[0];
    const float bt2 = fminf(fmaxf(beta2p[0], 0.0f), 1.0f);
    const float th2 = thr2p[0];

    // ---------------- phase 0: stage x[b] (c-major) and W1^T into LDS ----------------
    const float* xb = x + (size_t)b * (IN_SZ * T_STEPS);
    for (int i = tid; i < IN_SZ * T_STEPS; i += 1024) {
        const int c = i / T_STEPS;
        const int t = i - c * T_STEPS;
        xst[c * XT + t] = xb[i];             // lane-consecutive t: conflict-free
    }
    float* W1t = c2s;   // c2s free until phase 2; holds W1t[c*128 + h]
    for (int i = tid; i < IN_SZ * H_SZ; i += 1024) {
        const int h = i / IN_SZ;
        const int c = i - IN_SZ * h;
        W1t[c * H_SZ + h] = W1[i];
    }
    __syncthreads();

    // ---------------- per-thread layer-1 weights (one h-row) ----------------
    float w1r[IN_SZ];
#pragma unroll
    for (int c = 0; c < IN_SZ; ++c) w1r[c] = W1t[c * H_SZ + hown];
    const float b1r = b1[hown];

    // ---------------- phase 1: chunked cur1 GEMM pipelined with mem1 scan ----------------
    // chunk 0: all 16 waves emit (8-way t-interleave)
    emit_rows(cur1s[0], xst, w1r, b1r, 0, CHUNK, hown, jsl, 8);
    __syncthreads();

    float mem1 = 0.0f;
    for (int k = 0; k < 4; ++k) {
        if (tid < 128) {
            // scanner waves 0-1: boost priority on the serial recurrence chain
            __builtin_amdgcn_s_setprio(1);
            const int L = (k < 3) ? CHUNK : (T_STEPS - 3 * CHUNK);
            scan1_chunk(cur1s[k & 1], msh, k * CHUNK, L, tid, bt1, th1, mem1);
            __builtin_amdgcn_s_setprio(0);
        } else if (k < 3) {
            // waves 2-15: emit chunk k+1 (7-way t-interleave, jsl in 1..7)
            const int kn = k + 1;
            const int L = (kn < 3) ? CHUNK : (T_STEPS - 3 * CHUNK);
            emit_rows(cur1s[kn & 1], xst, w1r, b1r, kn * CHUNK, L, hown, jsl - 1, 7);
        }
        __syncthreads();
    }

    // ---------------- phase 2/3: stripe-pipelined cur2 GEMM + mem2 scan ----------------
    const int obase  = half ? 5 : 0;
    const int ntasks = half ? 4 : 5;

    float mem2 = 0.0f;
    const int o_sc = obase + lane;                       // scanner's output row (wave 7)
    float* out_spk = out + (size_t)b * OUT_SZ + o_sc;
    float* out_mem = out_spk + (size_t)T_STEPS * NBO;
    const float4* src4 = (const float4*)(c2s + lane * CPAD);

    for (int s = 0; s < 6; ++s) {
        if (wid < 7) {
            if (wid < ntasks) {
                const int o = obase + wid;
                const int t = s * 64 + lane;
                const int tc = (t < T_STEPS) ? t : (T_STEPS - 1);
                const uint4 mm = *(const uint4*)((const char*)msh + (size_t)tc * 16);
                const float* __restrict__ w2row = W2 + o * H_SZ;
                float acc = 0.0f;
#pragma unroll
                for (int h = 0; h < 32; ++h)
                    acc = fmaf((float)((mm.x >> h) & 1u), w2row[h], acc);
#pragma unroll
                for (int h = 0; h < 32; ++h)
                    acc = fmaf((float)((mm.y >> h) & 1u), w2row[32 + h], acc);
#pragma unroll
                for (int h = 0; h < 32; ++h)
                    acc = fmaf((float)((mm.z >> h) & 1u), w2row[64 + h], acc);
#pragma unroll
                for (int h = 0; h < 32; ++h)
                    acc = fmaf((float)((mm.w >> h) & 1u), w2row[96 + h], acc);
                c2s[wid * CPAD + t] = acc + b2[o];
            }
        } else if (wid == 7 && s > 0 && lane < ntasks) {
            // scanner wave 7: boost priority on the mem2 recurrence chain
            __builtin_amdgcn_s_setprio(1);
            const int sb = (s - 1) * 16;
            float4 fA = src4[sb], fB = src4[sb + 1];
#pragma unroll
            for (int i = 0; i < 16; ++i) {
                const float4 u = fA; fA = fB; fB = src4[sb + i + 2];
                const float vv[4] = { u.x, u.y, u.z, u.w };
#pragma unroll
                for (int kk = 0; kk < 4; ++kk) {
                    const int tt = (s - 1) * 64 + i * 4 + kk;
                    mem2 = fmaf(bt2, mem2, vv[kk]);
                    const bool p = mem2 > th2;
                    const float s2 = p ? 1.0f : 0.0f;
                    const float ms = mem2 - th2;     // == fmaf(-1, th2, mem2) bitwise
                    mem2 = p ? ms : mem2;
                    out_spk[(size_t)tt * NBO] = s2;
                    out_mem[(size_t)tt * NBO] = mem2;
                }
            }
            __builtin_amdgcn_s_setprio(0);
        }
        __syncthreads();
    }

    // tail: scan stripe 5 (steps 320..344, guarded)
    if (wid == 7 && lane < ntasks) {
        __builtin_amdgcn_s_setprio(1);
        const int sb = 5 * 16;
        float4 fA = src4[sb], fB = src4[sb + 1];
#pragma unroll
        for (int i = 0; i < 16; ++i) {
            const float4 u = fA; fA = fB; fB = src4[sb + i + 2];   // over-read in-bounds, discarded
            const float vv[4] = { u.x, u.y, u.z, u.w };
#pragma unroll
            for (int kk = 0; kk < 4; ++kk) {
                const int tt = 5 * 64 + i * 4 + kk;
                if (tt < T_STEPS) {
                    mem2 = fmaf(bt2, mem2, vv[kk]);
                    const bool p = mem2 > th2;
                    const float s2 = p ? 1.0f : 0.0f;
                    const float ms = mem2 - th2;
                    mem2 = p ? ms : mem2;
                    out_spk[(size_t)tt * NBO] = s2;
                    out_mem[(size_t)tt * NBO] = mem2;
                }
            }
        }
        __builtin_amdgcn_s_setprio(0);
    }
}

extern "C" void kernel_launch(void* const* d_in, const int* in_sizes, int n_in,
                              void* d_out, int out_size, void* d_ws, size_t ws_size,
                              hipStream_t stream) {
    const float* x     = (const float*)d_in[0];
    const float* W1    = (const float*)d_in[1];
    const float* b1    = (const float*)d_in[2];
    const float* W2    = (const float*)d_in[3];
    const float* b2    = (const float*)d_in[4];
    const float* beta1 = (const float*)d_in[5];
    const float* thr1  = (const float*)d_in[6];
    const float* beta2 = (const float*)d_in[7];
    const float* thr2  = (const float*)d_in[8];
    float* out = (float*)d_out;
    (void)in_sizes; (void)n_in; (void)out_size; (void)d_ws; (void)ws_size;

    snn_fused<<<dim3(B_SZ * 2), dim3(1024), 0, stream>>>(
        x, W1, b1, W2, b2, beta1, thr1, beta2, thr2, out);
}